// Round 9
// baseline (438.988 us; speedup 1.0000x reference)
//
#include <hip/hip_runtime.h>
#include <hip/hip_bf16.h>

#define Bn 16
#define Nn 4096
#define Pn 1024
#define Sn 32
#define Cn 64
#define EPSn 1e-5f
#define ALPHAn 0.2f
#define LOG2E 1.44269504088896341f

// ---- fp32 weight table (bias rows + prep staging) ----
#define W1O 0       // [68][64] k-order [feat64|xyz3|pad]
#define W2O 4352    // [64][64]
#define W3O 8448    // [64][128]
#define AO  16640   // two col-halves [132][64]; k-order [h3|xyz|pad]
#define B1O 33536
#define B2O 33600
#define B3O 33664
#define WSF 33792
__device__ __align__(16) float g_W[WSF];

// ---- FRAGMENT-MAJOR split-bf16 weights: g_Wf[frag][lane][8] u16 ----
// F5F fragments are pre-scaled by log2(e) so softmax uses exp2 directly.
#define F1F 0
#define F2F 24
#define F3F 40
#define F5F 72
#define NFRAG 152
#define WFU (NFRAG * 512)
__device__ __align__(16) unsigned short g_Wf[WFU];

// ---- row-major point store [b][n][68]; fps precompute; out1 staging ----
__device__ __align__(16) float g_pts[Bn * Nn * 68];
__device__ __align__(16) float g_fps[Bn * Pn * 132];   // [0..127]=ebias*log2e, [128..130]=new_xyz
__device__ __align__(16) float g_tmp[Bn * Pn * 128];

typedef __attribute__((ext_vector_type(8))) short short8;
typedef __attribute__((ext_vector_type(4))) float f32x4;

__device__ __forceinline__ void split2(float v, unsigned short& hu, unsigned short& lu) {
  __hip_bfloat16 h = __float2bfloat16(v);
  float hv = __bfloat162float(h);
  __hip_bfloat16 l = __float2bfloat16(v - hv);
  hu = *(unsigned short*)&h;
  lu = *(unsigned short*)&l;
}
__device__ __forceinline__ unsigned short bfh(float v) {
  __hip_bfloat16 h = __float2bfloat16(v);
  return *(unsigned short*)&h;
}
__device__ __forceinline__ float bf2f(unsigned short u) {
  __hip_bfloat16 h = *(__hip_bfloat16*)&u;
  return __bfloat162float(h);
}

#define MFMA_BF16 __builtin_amdgcn_mfma_f32_16x16x32_bf16
#define TERM3(Ci, Ahh, All, Bh, Bl) \
    Ci = MFMA_BF16(Ahh, Bh, Ci, 0, 0, 0); \
    Ci = MFMA_BF16(Ahh, Bl, Ci, 0, 0, 0); \
    Ci = MFMA_BF16(All, Bh, Ci, 0, 0, 0);

// Merged prep: blocks [0,1024) transpose points->g_pts; rest fold weights.
__global__ __launch_bounds__(256) void prep_kernel(
    const float* __restrict__ xyz, const float* __restrict__ points,
    const float* __restrict__ w1, const float* __restrict__ b1,
    const float* __restrict__ g1, const float* __restrict__ bt1,
    const float* __restrict__ m1, const float* __restrict__ v1,
    const float* __restrict__ w2, const float* __restrict__ b2,
    const float* __restrict__ g2, const float* __restrict__ bt2,
    const float* __restrict__ m2, const float* __restrict__ v2,
    const float* __restrict__ w3, const float* __restrict__ b3,
    const float* __restrict__ g3, const float* __restrict__ bt3,
    const float* __restrict__ m3, const float* __restrict__ v3,
    const float* __restrict__ a)
{
  if (blockIdx.x < 1024) {   // transpose tile
    __shared__ float T[68 * 65];
    const int t = threadIdx.x;
    const int b = blockIdx.x >> 6, n0 = (blockIdx.x & 63) << 6;
    const int nn = t & 63, cgrp = t >> 6;
    #pragma unroll
    for (int k = 0; k < 16; ++k) {
      const int c = cgrp * 16 + k;
      T[c * 65 + nn] = points[(b * Cn + c) * Nn + n0 + nn];
    }
    if (cgrp == 0) {
      #pragma unroll
      for (int d = 0; d < 3; ++d)
        T[(64 + d) * 65 + nn] = xyz[(b * 3 + d) * Nn + n0 + nn];
      T[67 * 65 + nn] = 0.f;
    }
    __syncthreads();
    const int row = t >> 2, part = t & 3;
    float* dst = g_pts + (((long)b << 12) + n0 + row) * 68 + part * 16;
    #pragma unroll
    for (int j = 0; j < 4; ++j) {
      const int o = part * 16 + j * 4;
      float4 v = { T[(o + 0) * 65 + row], T[(o + 1) * 65 + row],
                   T[(o + 2) * 65 + row], T[(o + 3) * 65 + row] };
      *(float4*)(dst + j * 4) = v;
    }
    if (part == 3) {
      float4 v = { T[64 * 65 + row], T[65 * 65 + row],
                   T[66 * 65 + row], T[67 * 65 + row] };
      *(float4*)(dst + 16) = v;
    }
    return;
  }
  const int idx = (blockIdx.x - 1024) * blockDim.x + threadIdx.x;
  if (idx < WSF) {
    float val;
    if (idx < W2O) {
      const int k = idx >> 6, o = idx & 63;
      const float sc = g1[o] * rsqrtf(v1[o] + EPSn);
      val = (k < 64) ? w1[o * 67 + 3 + k] * sc
          : (k < 67) ? w1[o * 67 + (k - 64)] * sc : 0.f;
    } else if (idx < W3O) {
      const int r = idx - W2O, k = r >> 6, o = r & 63;
      val = w2[o * 64 + k] * (g2[o] * rsqrtf(v2[o] + EPSn));
    } else if (idx < AO) {
      const int r = idx - W3O, k = r >> 7, o = r & 127;
      val = w3[o * 64 + k] * (g3[o] * rsqrtf(v3[o] + EPSn));
    } else if (idx < B1O) {
      int r = idx - AO;
      const int half = r / 8448; r -= half * 8448;
      const int k = r >> 6, o = half * 64 + (r & 63);
      val = (k < 128) ? a[(3 + k) * 128 + o]
          : (k < 131) ? a[(k - 128) * 128 + o] : 0.f;
    } else if (idx < B2O) {
      const int o = idx - B1O;
      val = (b1[o] - m1[o]) * (g1[o] * rsqrtf(v1[o] + EPSn)) + bt1[o];
    } else if (idx < B3O) {
      const int o = idx - B2O;
      val = (b2[o] - m2[o]) * (g2[o] * rsqrtf(v2[o] + EPSn)) + bt2[o];
    } else {
      const int o = idx - B3O;
      val = (b3[o] - m3[o]) * (g3[o] * rsqrtf(v3[o] + EPSn)) + bt3[o];
    }
    g_W[idx] = val;
  } else if (idx < WSF + WFU) {
    const int i = idx - WSF;
    const int frag = i >> 9, r = i & 511;
    const int lane = r >> 3, j = r & 7;
    const int quad = lane >> 4, nn = lane & 15;
    int plane, n, k;
    float w;
    if (frag < F2F) {                 // phase1: W1, C=2
      const int f = frag;
      plane = f & 1;
      const int c = (f >> 1) & 1, kcch = f >> 2, kc = kcch % 3, ch = kcch / 3;
      n = ch * 32 + c * 16 + nn; k = kc * 32 + quad * 8 + j;
      const float s = g1[n] * rsqrtf(v1[n] + EPSn);
      w = (k < 64) ? w1[n * 67 + 3 + k] * s
        : (k < 67) ? w1[n * 67 + (k - 64)] * s : 0.f;
    } else if (frag < F3F) {          // phase2: W2, C=2
      const int f = frag - F2F;
      plane = f & 1;
      const int c = (f >> 1) & 1, kc = (f >> 2) & 1, ch = f >> 3;
      n = ch * 32 + c * 16 + nn; k = kc * 32 + quad * 8 + j;
      w = w2[n * 64 + k] * (g2[n] * rsqrtf(v2[n] + EPSn));
    } else if (frag < F5F) {          // phase3: W3, C=4
      const int f = frag - F3F;
      plane = f & 1;
      const int c = (f >> 1) & 3, kc = (f >> 3) & 1, ch = f >> 4;
      n = ch * 64 + c * 16 + nn; k = kc * 32 + quad * 8 + j;
      w = w3[n * 64 + k] * (g3[n] * rsqrtf(v3[n] + EPSn));
    } else {                          // phase5: A, C=4, KC=5 — scaled by log2e
      const int f = frag - F5F;
      plane = f & 1;
      const int c = (f >> 1) & 3, kcch = f >> 3, kc = kcch % 5, ch = kcch / 5;
      n = ch * 64 + c * 16 + nn; k = kc * 32 + quad * 8 + j;
      w = ((k < 128) ? a[(3 + k) * 128 + n]
        : (k < 131) ? a[(k - 128) * 128 + n] : 0.f) * LOG2E;
    }
    unsigned short hu, lu; split2(w, hu, lu);
    g_Wf[i] = plane ? lu : hu;
  }
}

// ---- shared LDS strides ----
#define XAs 88    // u16 stride (fps kernel only)
#define XHs 152   // u16 stride; bank step 12 mod 32 -> balanced b128 reads

// fps MLP+ebias via MFMA: 16 points/block, 1024 blocks. Split-bf16
// activations, 3-term products ~= fp32 precision.
__global__ __launch_bounds__(256) void fps_kernel(
    const int* __restrict__ fps_idx, float* __restrict__ out)
{
  __shared__ __align__(16) unsigned char LB[15376];
  unsigned short* XAh = (unsigned short*)(LB + 0);
  unsigned short* XAl = (unsigned short*)(LB + 2816);
  unsigned short* XHh = (unsigned short*)(LB + 5632);
  unsigned short* XHl = (unsigned short*)(LB + 10496);
  unsigned short* ZS  = (unsigned short*)(LB + 15360);

  const int t = threadIdx.x, lane = t & 63, w = t >> 6;
  const int quad = lane >> 4, nn = lane & 15;
  const int ch = w >> 1, cl = w & 1;
  const int blk = ((blockIdx.x & 7) << 7) | (blockIdx.x >> 3);  // XCD swizzle
  const int g0 = blk * 16;

  if (t < 4) ((float*)ZS)[t] = 0.f;

  // gather 16 fps rows, split hi/lo
  if (t < 128) {
    const int s0 = t >> 3, cg = t & 7;
    const int gp = g0 + s0, b = gp >> 10, p = gp & 1023;
    const int fi = fps_idx[gp];
    const float* frow = g_pts + (((long)b << 12) + fi) * 68;
    const int c0 = cg * 8;
    const float4 va = *(const float4*)(frow + c0);
    const float4 vb = *(const float4*)(frow + c0 + 4);
    short8 hv, lv;
    unsigned short hu, lu;
    split2(va.x, hu, lu); hv[0] = (short)hu; lv[0] = (short)lu;
    split2(va.y, hu, lu); hv[1] = (short)hu; lv[1] = (short)lu;
    split2(va.z, hu, lu); hv[2] = (short)hu; lv[2] = (short)lu;
    split2(va.w, hu, lu); hv[3] = (short)hu; lv[3] = (short)lu;
    split2(vb.x, hu, lu); hv[4] = (short)hu; lv[4] = (short)lu;
    split2(vb.y, hu, lu); hv[5] = (short)hu; lv[5] = (short)lu;
    split2(vb.z, hu, lu); hv[6] = (short)hu; lv[6] = (short)lu;
    split2(vb.w, hu, lu); hv[7] = (short)hu; lv[7] = (short)lu;
    *(short8*)(XAh + s0 * XAs + c0) = hv;
    *(short8*)(XAl + s0 * XAs + c0) = lv;
    if (cg == 0) {
      #pragma unroll
      for (int d = 0; d < 3; ++d) {
        const float v = frow[64 + d];
        unsigned short h2, l2; split2(v, h2, l2);
        XAh[s0 * XAs + 64 + d] = h2; XAl[s0 * XAs + 64 + d] = l2;
        XHh[s0 * XHs + 128 + d] = h2; XHl[s0 * XHs + 128 + d] = l2;
        out[(b * 3 + d) * Pn + p] = v;
        g_fps[(long)gp * 132 + 128 + d] = v;
      }
    } else if (cg == 1) {
      #pragma unroll
      for (int j = 0; j < 13; ++j) { XAh[s0 * XAs + 67 + j] = 0; XAl[s0 * XAs + 67 + j] = 0; }
    } else if (cg == 2) {
      #pragma unroll
      for (int j = 0; j < 13; ++j) { XHh[s0 * XHs + 131 + j] = 0; XHl[s0 * XHs + 131 + j] = 0; }
    }
  }
  __syncthreads();

  f32x4 C[2];
  const int col1 = w * 16 + nn;

  // Phase 1: X(K96) @ W1 -> h1 (bias in acc init)
  {
    const float bb = g_W[B1O + col1];
    C[0] = (f32x4){bb, bb, bb, bb};
  }
  #pragma unroll
  for (int kc = 0; kc < 3; ++kc) {
    const int ka = kc * 32 + quad * 8;
    const short8 A0h = (ka < 80) ? *(const short8*)(XAh + nn * XAs + ka) : *(const short8*)ZS;
    const short8 A0l = (ka < 80) ? *(const short8*)(XAl + nn * XAs + ka) : *(const short8*)ZS;
    const unsigned short* pf = g_Wf + (((ch * 3 + kc) * 2 + cl) * 2) * 512 + lane * 8;
    const short8 Bh = *(const short8*)pf, Bl = *(const short8*)(pf + 512);
    TERM3(C[0], A0h, A0l, Bh, Bl);
  }
  #pragma unroll
  for (int r = 0; r < 4; ++r) {
    const float v = fmaxf(C[0][r], 0.f);
    unsigned short hu, lu; split2(v, hu, lu);
    XHh[(quad * 4 + r) * XHs + col1] = hu;
    XHl[(quad * 4 + r) * XHs + col1] = lu;
  }
  __syncthreads();

  // Phase 2: h1(K64) @ W2 -> h2
  {
    const float bb = g_W[B2O + col1];
    C[0] = (f32x4){bb, bb, bb, bb};
  }
  #pragma unroll
  for (int kc = 0; kc < 2; ++kc) {
    const int ka = kc * 32 + quad * 8;
    const short8 A0h = *(const short8*)(XHh + nn * XHs + ka);
    const short8 A0l = *(const short8*)(XHl + nn * XHs + ka);
    const unsigned short* pf = g_Wf + (F2F + ((ch * 2 + kc) * 2 + cl) * 2) * 512 + lane * 8;
    const short8 Bh = *(const short8*)pf, Bl = *(const short8*)(pf + 512);
    TERM3(C[0], A0h, A0l, Bh, Bl);
  }
  __syncthreads();
  #pragma unroll
  for (int r = 0; r < 4; ++r) {
    const float v = fmaxf(C[0][r], 0.f);
    unsigned short hu, lu; split2(v, hu, lu);
    XAh[(quad * 4 + r) * XAs + col1] = hu;
    XAl[(quad * 4 + r) * XAs + col1] = lu;
  }
  __syncthreads();

  // Phase 3: h2(K64) @ W3 -> h3 (128 cols)
  {
    const float b0 = g_W[B3O + w * 32 + nn];
    const float b1 = g_W[B3O + w * 32 + 16 + nn];
    C[0] = (f32x4){b0, b0, b0, b0};
    C[1] = (f32x4){b1, b1, b1, b1};
  }
  #pragma unroll
  for (int kc = 0; kc < 2; ++kc) {
    const int ka = kc * 32 + quad * 8;
    const short8 A0h = *(const short8*)(XAh + nn * XAs + ka);
    const short8 A0l = *(const short8*)(XAl + nn * XAs + ka);
    #pragma unroll
    for (int c2 = 0; c2 < 2; ++c2) {
      const unsigned short* pf = g_Wf + (F3F + ((ch * 2 + kc) * 4 + cl * 2 + c2) * 2) * 512 + lane * 8;
      const short8 Bh = *(const short8*)pf, Bl = *(const short8*)(pf + 512);
      TERM3(C[c2], A0h, A0l, Bh, Bl);
    }
  }
  __syncthreads();
  #pragma unroll
  for (int c2 = 0; c2 < 2; ++c2) {
    const int col = w * 32 + c2 * 16 + nn;
    #pragma unroll
    for (int r = 0; r < 4; ++r) {
      const float v = fmaxf(C[c2][r], 0.f);
      unsigned short hu, lu; split2(v, hu, lu);
      XHh[(quad * 4 + r) * XHs + col] = hu;
      XHl[(quad * 4 + r) * XHs + col] = lu;
    }
  }
  __syncthreads();

  // Phase 5: [h3|xyz](K160) @ A(log2e-scaled) -> ebias' -> g_fps
  C[0] = (f32x4){0.f,0.f,0.f,0.f}; C[1] = C[0];
  #pragma unroll
  for (int kc = 0; kc < 5; ++kc) {
    const int ka = kc * 32 + quad * 8;
    const short8 A0h = (ka < 144) ? *(const short8*)(XHh + nn * XHs + ka) : *(const short8*)ZS;
    const short8 A0l = (ka < 144) ? *(const short8*)(XHl + nn * XHs + ka) : *(const short8*)ZS;
    #pragma unroll
    for (int c2 = 0; c2 < 2; ++c2) {
      const unsigned short* pf = g_Wf + (F5F + ((ch * 5 + kc) * 4 + cl * 2 + c2) * 2) * 512 + lane * 8;
      const short8 Bh = *(const short8*)pf, Bl = *(const short8*)(pf + 512);
      TERM3(C[c2], A0h, A0l, Bh, Bl);
    }
  }
  #pragma unroll
  for (int c2 = 0; c2 < 2; ++c2) {
    const int col = w * 32 + c2 * 16 + nn;
    #pragma unroll
    for (int r = 0; r < 4; ++r)
      g_fps[(long)(g0 + quad * 4 + r) * 132 + col] = C[c2][r];
  }
}

// Epilogue: g_tmp[b][p][128] -> out1[b][c][p]
__global__ __launch_bounds__(256) void transpose_out(float* __restrict__ out)
{
  __shared__ float T[64 * 129];
  const int t = threadIdx.x;
  const int b = blockIdx.x >> 4, p0 = (blockIdx.x & 15) << 6;
  const int c = t & 127, ph = t >> 7;
  #pragma unroll
  for (int pp = 0; pp < 32; ++pp) {
    const int pi = ph * 32 + pp;
    T[pi * 129 + c] = g_tmp[(((long)b << 10) + p0 + pi) * 128 + c];
  }
  __syncthreads();
  const int pn = t & 63, cg = t >> 6;
  #pragma unroll
  for (int k = 0; k < 32; ++k) {
    const int cc = cg * 32 + k;
    out[Bn * 3 * Pn + ((b << 7) + cc) * Pn + p0 + pn] = T[pn * 129 + cc];
  }
}

// ---- fused kernel: 2 groups per block, ONE overlaid [32][152] buffer per
// group. Register-pressure-restructured to fit the 64-reg/32-wave band:
//   - phase 3 runs the two groups SEQUENTIALLY (4 accumulators peak; F3F
//     weights read twice per block, +10% L2 weight traffic)
//   - phase 5 runs per-c2 slices with FUSED softmax (4 accumulators peak;
//     weights still read exactly once)
// R8 lesson: at launch_bounds caps 64/73 the old 8-acc structure spilled
// ~16-32 B/thread to scratch (WRITE_SIZE 73-337 MB vs 8.4 MB program writes).
#define OXB0 0            // 32*152*2 = 9728
#define OXB1 9728         // -> 19456
#define OZS  19456        // 16 B zero stub -> 19472
#define LDSB 19472

// FS float at hole: row (cc>>2), u16 col 144 + (cc&3)*2  (4B-aligned)
#define FS_PTR(XBg, cc) ((float*)((XBg) + ((cc) >> 2) * XHs + 144 + ((cc) & 3) * 2))

__global__ __launch_bounds__(256, 8) void fused_kernel(
    const int* __restrict__ group_idx)
{
  __shared__ __align__(16) unsigned char LB[LDSB];
  unsigned short* const XB0 = (unsigned short*)(LB + OXB0);
  unsigned short* const XB1 = (unsigned short*)(LB + OXB1);
  unsigned short* ZS = (unsigned short*)(LB + OZS);

  const int t = threadIdx.x, lane = t & 63, w = t >> 6;
  const int quad = lane >> 4, nn = lane & 15;
  const int ch = w >> 1, cl = w & 1;
  // XCD swizzle: 8192 blocks -> each XCD gets 1024 contiguous blocks
  const int blk = ((blockIdx.x & 7) << 10) | (blockIdx.x >> 3);
  const int base = blk * 2;            // groups base, base+1 (same b always)
  const int b = base >> 10;

  // ---- S0: stage ebias' into XB padding holes; zero stub ----
  {
    const int gi = t >> 7, cc = t & 127;
    unsigned short* XBg = gi ? XB1 : XB0;
    *FS_PTR(XBg, cc) = g_fps[(long)(base + gi) * 132 + cc];
  }
  if (t < 4) ((float*)ZS)[t] = 0.f;

  // ---- S1: gather group rows; rxyz at 64..66 AND 128..130; zero pads ----
  {
    const int s0 = t >> 3, cg = t & 7;
    const int c0 = cg * 8;
    #pragma unroll
    for (int gi = 0; gi < 2; ++gi) {
      unsigned short* XBg = gi ? XB1 : XB0;
      const int gidx = group_idx[(base + gi) * Sn + s0];
      const float* prow = g_pts + (((long)b << 12) + gidx) * 68;
      const float4 va = *(const float4*)(prow + c0);
      const float4 vb = *(const float4*)(prow + c0 + 4);
      unsigned q0, q1, q2, q3;
      asm("v_cvt_pk_bf16_f32 %0, %1, %2" : "=v"(q0) : "v"(va.x), "v"(va.y));
      asm("v_cvt_pk_bf16_f32 %0, %1, %2" : "=v"(q1) : "v"(va.z), "v"(va.w));
      asm("v_cvt_pk_bf16_f32 %0, %1, %2" : "=v"(q2) : "v"(vb.x), "v"(vb.y));
      asm("v_cvt_pk_bf16_f32 %0, %1, %2" : "=v"(q3) : "v"(vb.z), "v"(vb.w));
      uint4 hv = {q0, q1, q2, q3};
      *(uint4*)(XBg + s0 * XHs + c0) = hv;
      if (cg == 0) {
        #pragma unroll
        for (int d = 0; d < 3; ++d) {
          const float r = prow[64 + d] - g_fps[(long)(base + gi) * 132 + 128 + d];
          const unsigned short hu = bfh(r);
          XBg[s0 * XHs + 64 + d] = hu;
          XBg[s0 * XHs + 128 + d] = hu;
        }
      } else if (cg == 1) {
        #pragma unroll
        for (int j = 0; j < 15; ++j) XBg[s0 * XHs + 67 + j] = 0;   // 67..81
      } else if (cg == 2) {
        #pragma unroll
        for (int j = 0; j < 14; ++j) XBg[s0 * XHs + 82 + j] = 0;   // 82..95
      } else if (cg == 3) {
        #pragma unroll
        for (int j = 0; j < 13; ++j) XBg[s0 * XHs + 131 + j] = 0;  // 131..143
      }
    }
  }
  __syncthreads();

  const int col1 = w * 16 + nn;

  // ===== Phase 1: X(cols 0..95) @ W1f -> h1 (cols 0..63) =====
  {
    f32x4 C00, C01, C10, C11;
    const float bb = g_W[B1O + col1];
    C00 = (f32x4){bb, bb, bb, bb};
    C01 = C00; C10 = C00; C11 = C00;
    #pragma unroll
    for (int kc = 0; kc < 3; ++kc) {
      const int ka = kc * 32 + quad * 8;
      const unsigned short* pf = g_Wf + (((ch * 3 + kc) * 2 + cl) * 2) * 512 + lane * 8;
      const short8 Bh = *(const short8*)pf, Bl = *(const short8*)(pf + 512);
      const short8 A00 = *(const short8*)(XB0 + nn * XHs + ka);
      const short8 A01 = *(const short8*)(XB0 + (16 + nn) * XHs + ka);
      const short8 A10 = *(const short8*)(XB1 + nn * XHs + ka);
      const short8 A11 = *(const short8*)(XB1 + (16 + nn) * XHs + ka);
      C00 = MFMA_BF16(A00, Bh, C00, 0, 0, 0);
      C00 = MFMA_BF16(A00, Bl, C00, 0, 0, 0);
      C01 = MFMA_BF16(A01, Bh, C01, 0, 0, 0);
      C01 = MFMA_BF16(A01, Bl, C01, 0, 0, 0);
      C10 = MFMA_BF16(A10, Bh, C10, 0, 0, 0);
      C10 = MFMA_BF16(A10, Bl, C10, 0, 0, 0);
      C11 = MFMA_BF16(A11, Bh, C11, 0, 0, 0);
      C11 = MFMA_BF16(A11, Bl, C11, 0, 0, 0);
    }
    __syncthreads();   // all X reads complete before h1 overwrites cols 0..63
    #pragma unroll
    for (int r = 0; r < 4; ++r) {
      XB0[(quad * 4 + r) * XHs + col1]      = bfh(fmaxf(C00[r], 0.f));
      XB0[(16 + quad * 4 + r) * XHs + col1] = bfh(fmaxf(C01[r], 0.f));
      XB1[(quad * 4 + r) * XHs + col1]      = bfh(fmaxf(C10[r], 0.f));
      XB1[(16 + quad * 4 + r) * XHs + col1] = bfh(fmaxf(C11[r], 0.f));
    }
  }
  __syncthreads();

  // ===== Phase 2: h1(cols 0..63) @ W2f -> h2 (cols 64..127, disjoint) =====
  {
    f32x4 C00, C01, C10, C11;
    const float bb = g_W[B2O + col1];
    C00 = (f32x4){bb, bb, bb, bb};
    C01 = C00; C10 = C00; C11 = C00;
    #pragma unroll
    for (int kc = 0; kc < 2; ++kc) {
      const int ka = kc * 32 + quad * 8;
      const unsigned short* pf = g_Wf + (F2F + ((ch * 2 + kc) * 2 + cl) * 2) * 512 + lane * 8;
      const short8 Bh = *(const short8*)pf, Bl = *(const short8*)(pf + 512);
      const short8 A00 = *(const short8*)(XB0 + nn * XHs + ka);
      const short8 A01 = *(const short8*)(XB0 + (16 + nn) * XHs + ka);
      const short8 A10 = *(const short8*)(XB1 + nn * XHs + ka);
      const short8 A11 = *(const short8*)(XB1 + (16 + nn) * XHs + ka);
      C00 = MFMA_BF16(A00, Bh, C00, 0, 0, 0);
      C00 = MFMA_BF16(A00, Bl, C00, 0, 0, 0);
      C01 = MFMA_BF16(A01, Bh, C01, 0, 0, 0);
      C01 = MFMA_BF16(A01, Bl, C01, 0, 0, 0);
      C10 = MFMA_BF16(A10, Bh, C10, 0, 0, 0);
      C10 = MFMA_BF16(A10, Bl, C10, 0, 0, 0);
      C11 = MFMA_BF16(A11, Bh, C11, 0, 0, 0);
      C11 = MFMA_BF16(A11, Bl, C11, 0, 0, 0);
    }
    #pragma unroll
    for (int r = 0; r < 4; ++r) {
      XB0[(quad * 4 + r) * XHs + 64 + col1]      = bfh(fmaxf(C00[r], 0.f));
      XB0[(16 + quad * 4 + r) * XHs + 64 + col1] = bfh(fmaxf(C01[r], 0.f));
      XB1[(quad * 4 + r) * XHs + 64 + col1]      = bfh(fmaxf(C10[r], 0.f));
      XB1[(16 + quad * 4 + r) * XHs + 64 + col1] = bfh(fmaxf(C11[r], 0.f));
    }
  }
  __syncthreads();

  // ===== Phase 3: h2(cols 64..127) @ W3f -> h3 (cols 0..127), PER GROUP ====
  // Sequential groups: peak 4 accumulators. F3F fragments read twice/block.
  #pragma unroll 1
  for (int gi = 0; gi < 2; ++gi) {
    unsigned short* const XBg = gi ? XB1 : XB0;
    f32x4 C[4];   // [mi*2+c2]
    const float b0 = g_W[B3O + w * 32 + nn];
    const float b1 = g_W[B3O + w * 32 + 16 + nn];
    C[0] = (f32x4){b0, b0, b0, b0};
    C[1] = (f32x4){b1, b1, b1, b1};
    C[2] = C[0]; C[3] = C[1];
    #pragma unroll
    for (int kc = 0; kc < 2; ++kc) {
      const int ka = 64 + kc * 32 + quad * 8;
      const short8 A0 = *(const short8*)(XBg + nn * XHs + ka);
      const short8 A1 = *(const short8*)(XBg + (16 + nn) * XHs + ka);
      #pragma unroll
      for (int c2 = 0; c2 < 2; ++c2) {
        const unsigned short* pf = g_Wf + (F3F + ((ch * 2 + kc) * 4 + cl * 2 + c2) * 2) * 512 + lane * 8;
        const short8 Bh = *(const short8*)pf, Bl = *(const short8*)(pf + 512);
        C[0 + c2] = MFMA_BF16(A0, Bh, C[0 + c2], 0, 0, 0);
        C[0 + c2] = MFMA_BF16(A0, Bl, C[0 + c2], 0, 0, 0);
        C[2 + c2] = MFMA_BF16(A1, Bh, C[2 + c2], 0, 0, 0);
        C[2 + c2] = MFMA_BF16(A1, Bl, C[2 + c2], 0, 0, 0);
      }
    }
    __syncthreads();   // all h2 reads of XBg complete before h3 overwrite
    #pragma unroll
    for (int c2 = 0; c2 < 2; ++c2) {
      const int col = w * 32 + c2 * 16 + nn;
      #pragma unroll
      for (int r = 0; r < 4; ++r) {
        XBg[(quad * 4 + r) * XHs + col]      = bfh(fmaxf(C[0 + c2][r], 0.f));
        XBg[(16 + quad * 4 + r) * XHs + col] = bfh(fmaxf(C[2 + c2][r], 0.f));
      }
    }
  }
  __syncthreads();

  // ===== Phase 5: [h3|rxyz] @ Af(log2e) -> scores, PER c2 SLICE with =====
  // fused softmax+pool. Peak 4 accumulators; each weight frag read once.
  #pragma unroll 1
  for (int c2 = 0; c2 < 2; ++c2) {
    const int col = w * 32 + c2 * 16 + nn;
    f32x4 P00, P01, P10, P11;   // [group][mi]
    {
      const float e0 = *FS_PTR(XB0, col);
      const float e1 = *FS_PTR(XB1, col);
      P00 = (f32x4){-e0, -e0, -e0, -e0}; P01 = P00;
      P10 = (f32x4){-e1, -e1, -e1, -e1}; P11 = P10;
    }
    #pragma unroll
    for (int kc = 0; kc < 5; ++kc) {
      const int ka = kc * 32 + quad * 8;
      const short8 A00 = (ka < 144) ? *(const short8*)(XB0 + nn * XHs + ka) : *(const short8*)ZS;
      const short8 A01 = (ka < 144) ? *(const short8*)(XB0 + (16 + nn) * XHs + ka) : *(const short8*)ZS;
      const short8 A10 = (ka < 144) ? *(const short8*)(XB1 + nn * XHs + ka) : *(const short8*)ZS;
      const short8 A11 = (ka < 144) ? *(const short8*)(XB1 + (16 + nn) * XHs + ka) : *(const short8*)ZS;
      const unsigned short* pf = g_Wf + (F5F + ((ch * 5 + kc) * 4 + cl * 2 + c2) * 2) * 512 + lane * 8;
      const short8 Bh = *(const short8*)pf, Bl = *(const short8*)(pf + 512);
      P00 = MFMA_BF16(A00, Bh, P00, 0, 0, 0);
      P00 = MFMA_BF16(A00, Bl, P00, 0, 0, 0);
      P01 = MFMA_BF16(A01, Bh, P01, 0, 0, 0);
      P01 = MFMA_BF16(A01, Bl, P01, 0, 0, 0);
      P10 = MFMA_BF16(A10, Bh, P10, 0, 0, 0);
      P10 = MFMA_BF16(A10, Bl, P10, 0, 0, 0);
      P11 = MFMA_BF16(A11, Bh, P11, 0, 0, 0);
      P11 = MFMA_BF16(A11, Bl, P11, 0, 0, 0);
    }
    // fused wave-local softmax + pool for this 16-col slice, both groups
    #pragma unroll
    for (int gi = 0; gi < 2; ++gi) {
      f32x4& Pa = gi ? P10 : P00;
      f32x4& Pb = gi ? P11 : P01;
      unsigned short* const XBg = gi ? XB1 : XB0;
      float tmin = 3.4e38f;
      #pragma unroll
      for (int r = 0; r < 4; ++r) {
        const float ta = fminf(Pa[r], 0.2f * Pa[r]);
        const float tb = fminf(Pb[r], 0.2f * Pb[r]);
        Pa[r] = ta; Pb[r] = tb;
        tmin = fminf(tmin, fminf(ta, tb));
      }
      tmin = fminf(tmin, __shfl_xor(tmin, 16));
      tmin = fminf(tmin, __shfl_xor(tmin, 32));
      float den = 0.f, pool = 0.f;
      #pragma unroll
      for (int r = 0; r < 4; ++r) {
        const float wa = __builtin_amdgcn_exp2f(tmin - Pa[r]);
        const float wb = __builtin_amdgcn_exp2f(tmin - Pb[r]);
        den += wa + wb;
        pool = fmaf(wa, bf2f(XBg[(quad * 4 + r) * XHs + col]), pool);
        pool = fmaf(wb, bf2f(XBg[(16 + quad * 4 + r) * XHs + col]), pool);
      }
      den  += __shfl_xor(den, 16);  den  += __shfl_xor(den, 32);
      pool += __shfl_xor(pool, 16); pool += __shfl_xor(pool, 32);
      if (quad == 0)
        g_tmp[(long)(base + gi) * 128 + col] =
            pool * __builtin_amdgcn_rcpf(den);
    }
  }
}

extern "C" void kernel_launch(void* const* d_in, const int* in_sizes, int n_in,
                              void* d_out, int out_size, void* d_ws, size_t ws_size,
                              hipStream_t stream) {
  const float* xyz       = (const float*)d_in[0];
  const float* points    = (const float*)d_in[1];
  const int*   fps_idx   = (const int*)d_in[2];
  const int*   group_idx = (const int*)d_in[3];

  const int prep_blocks = 1024 + (WSF + WFU + 255) / 256;
  prep_kernel<<<prep_blocks, 256, 0, stream>>>(
      xyz, points,
      (const float*)d_in[4],  (const float*)d_in[5],
      (const float*)d_in[6],  (const float*)d_in[7],
      (const float*)d_in[8],  (const float*)d_in[9],
      (const float*)d_in[10], (const float*)d_in[11],
      (const float*)d_in[12], (const float*)d_in[13],
      (const float*)d_in[14], (const float*)d_in[15],
      (const float*)d_in[16], (const float*)d_in[17],
      (const float*)d_in[18], (const float*)d_in[19],
      (const float*)d_in[20], (const float*)d_in[21],
      (const float*)d_in[22]);

  fps_kernel<<<1024, 256, 0, stream>>>(fps_idx, (float*)d_out);

  fused_kernel<<<Bn * Pn / 2, 256, 0, stream>>>(group_idx);

  transpose_out<<<Bn * 16, 256, 0, stream>>>((float*)d_out);
}

// Round 10
// 221.221 us; speedup vs baseline: 1.9844x; 1.9844x over previous
//
#include <hip/hip_runtime.h>
#include <hip/hip_bf16.h>

#define Bn 16
#define Nn 4096
#define Pn 1024
#define Sn 32
#define Cn 64
#define EPSn 1e-5f
#define ALPHAn 0.2f
#define LOG2E 1.44269504088896341f

// ---- fp32 weight table (bias rows + prep staging) ----
#define W1O 0       // [68][64] k-order [feat64|xyz3|pad]
#define W2O 4352    // [64][64]
#define W3O 8448    // [64][128]
#define AO  16640   // two col-halves [132][64]; k-order [h3|xyz|pad]
#define B1O 33536
#define B2O 33600
#define B3O 33664
#define WSF 33792
__device__ __align__(16) float g_W[WSF];

// ---- FRAGMENT-MAJOR split-bf16 weights: g_Wf[frag][lane][8] u16 ----
// F5F fragments are pre-scaled by log2(e) so softmax uses exp2 directly.
#define F1F 0
#define F2F 24
#define F3F 40
#define F5F 72
#define NFRAG 152
#define WFU (NFRAG * 512)
__device__ __align__(16) unsigned short g_Wf[WFU];

// ---- row-major point store [b][n][68]; fps precompute; out1 staging ----
__device__ __align__(16) float g_pts[Bn * Nn * 68];
__device__ __align__(16) float g_fps[Bn * Pn * 132];   // [0..127]=ebias*log2e, [128..130]=new_xyz
__device__ __align__(16) float g_tmp[Bn * Pn * 128];

typedef __attribute__((ext_vector_type(8))) short short8;
typedef __attribute__((ext_vector_type(4))) float f32x4;

__device__ __forceinline__ void split2(float v, unsigned short& hu, unsigned short& lu) {
  __hip_bfloat16 h = __float2bfloat16(v);
  float hv = __bfloat162float(h);
  __hip_bfloat16 l = __float2bfloat16(v - hv);
  hu = *(unsigned short*)&h;
  lu = *(unsigned short*)&l;
}
__device__ __forceinline__ unsigned short bfh(float v) {
  __hip_bfloat16 h = __float2bfloat16(v);
  return *(unsigned short*)&h;
}
__device__ __forceinline__ float bf2f(unsigned short u) {
  __hip_bfloat16 h = *(__hip_bfloat16*)&u;
  return __bfloat162float(h);
}

#define MFMA_BF16 __builtin_amdgcn_mfma_f32_16x16x32_bf16
#define TERM3(Ci, Ahh, All, Bh, Bl) \
    Ci = MFMA_BF16(Ahh, Bh, Ci, 0, 0, 0); \
    Ci = MFMA_BF16(Ahh, Bl, Ci, 0, 0, 0); \
    Ci = MFMA_BF16(All, Bh, Ci, 0, 0, 0);

// Merged prep: blocks [0,1024) transpose points->g_pts; rest fold weights.
__global__ __launch_bounds__(256) void prep_kernel(
    const float* __restrict__ xyz, const float* __restrict__ points,
    const float* __restrict__ w1, const float* __restrict__ b1,
    const float* __restrict__ g1, const float* __restrict__ bt1,
    const float* __restrict__ m1, const float* __restrict__ v1,
    const float* __restrict__ w2, const float* __restrict__ b2,
    const float* __restrict__ g2, const float* __restrict__ bt2,
    const float* __restrict__ m2, const float* __restrict__ v2,
    const float* __restrict__ w3, const float* __restrict__ b3,
    const float* __restrict__ g3, const float* __restrict__ bt3,
    const float* __restrict__ m3, const float* __restrict__ v3,
    const float* __restrict__ a)
{
  if (blockIdx.x < 1024) {   // transpose tile
    __shared__ float T[68 * 65];
    const int t = threadIdx.x;
    const int b = blockIdx.x >> 6, n0 = (blockIdx.x & 63) << 6;
    const int nn = t & 63, cgrp = t >> 6;
    #pragma unroll
    for (int k = 0; k < 16; ++k) {
      const int c = cgrp * 16 + k;
      T[c * 65 + nn] = points[(b * Cn + c) * Nn + n0 + nn];
    }
    if (cgrp == 0) {
      #pragma unroll
      for (int d = 0; d < 3; ++d)
        T[(64 + d) * 65 + nn] = xyz[(b * 3 + d) * Nn + n0 + nn];
      T[67 * 65 + nn] = 0.f;
    }
    __syncthreads();
    const int row = t >> 2, part = t & 3;
    float* dst = g_pts + (((long)b << 12) + n0 + row) * 68 + part * 16;
    #pragma unroll
    for (int j = 0; j < 4; ++j) {
      const int o = part * 16 + j * 4;
      float4 v = { T[(o + 0) * 65 + row], T[(o + 1) * 65 + row],
                   T[(o + 2) * 65 + row], T[(o + 3) * 65 + row] };
      *(float4*)(dst + j * 4) = v;
    }
    if (part == 3) {
      float4 v = { T[64 * 65 + row], T[65 * 65 + row],
                   T[66 * 65 + row], T[67 * 65 + row] };
      *(float4*)(dst + 16) = v;
    }
    return;
  }
  const int idx = (blockIdx.x - 1024) * blockDim.x + threadIdx.x;
  if (idx < WSF) {
    float val;
    if (idx < W2O) {
      const int k = idx >> 6, o = idx & 63;
      const float sc = g1[o] * rsqrtf(v1[o] + EPSn);
      val = (k < 64) ? w1[o * 67 + 3 + k] * sc
          : (k < 67) ? w1[o * 67 + (k - 64)] * sc : 0.f;
    } else if (idx < W3O) {
      const int r = idx - W2O, k = r >> 6, o = r & 63;
      val = w2[o * 64 + k] * (g2[o] * rsqrtf(v2[o] + EPSn));
    } else if (idx < AO) {
      const int r = idx - W3O, k = r >> 7, o = r & 127;
      val = w3[o * 64 + k] * (g3[o] * rsqrtf(v3[o] + EPSn));
    } else if (idx < B1O) {
      int r = idx - AO;
      const int half = r / 8448; r -= half * 8448;
      const int k = r >> 6, o = half * 64 + (r & 63);
      val = (k < 128) ? a[(3 + k) * 128 + o]
          : (k < 131) ? a[(k - 128) * 128 + o] : 0.f;
    } else if (idx < B2O) {
      const int o = idx - B1O;
      val = (b1[o] - m1[o]) * (g1[o] * rsqrtf(v1[o] + EPSn)) + bt1[o];
    } else if (idx < B3O) {
      const int o = idx - B2O;
      val = (b2[o] - m2[o]) * (g2[o] * rsqrtf(v2[o] + EPSn)) + bt2[o];
    } else {
      const int o = idx - B3O;
      val = (b3[o] - m3[o]) * (g3[o] * rsqrtf(v3[o] + EPSn)) + bt3[o];
    }
    g_W[idx] = val;
  } else if (idx < WSF + WFU) {
    const int i = idx - WSF;
    const int frag = i >> 9, r = i & 511;
    const int lane = r >> 3, j = r & 7;
    const int quad = lane >> 4, nn = lane & 15;
    int plane, n, k;
    float w;
    if (frag < F2F) {                 // phase1: W1, C=2
      const int f = frag;
      plane = f & 1;
      const int c = (f >> 1) & 1, kcch = f >> 2, kc = kcch % 3, ch = kcch / 3;
      n = ch * 32 + c * 16 + nn; k = kc * 32 + quad * 8 + j;
      const float s = g1[n] * rsqrtf(v1[n] + EPSn);
      w = (k < 64) ? w1[n * 67 + 3 + k] * s
        : (k < 67) ? w1[n * 67 + (k - 64)] * s : 0.f;
    } else if (frag < F3F) {          // phase2: W2, C=2
      const int f = frag - F2F;
      plane = f & 1;
      const int c = (f >> 1) & 1, kc = (f >> 2) & 1, ch = f >> 3;
      n = ch * 32 + c * 16 + nn; k = kc * 32 + quad * 8 + j;
      w = w2[n * 64 + k] * (g2[n] * rsqrtf(v2[n] + EPSn));
    } else if (frag < F5F) {          // phase3: W3, C=4
      const int f = frag - F3F;
      plane = f & 1;
      const int c = (f >> 1) & 3, kc = (f >> 3) & 1, ch = f >> 4;
      n = ch * 64 + c * 16 + nn; k = kc * 32 + quad * 8 + j;
      w = w3[n * 64 + k] * (g3[n] * rsqrtf(v3[n] + EPSn));
    } else {                          // phase5: A, C=4, KC=5 — scaled by log2e
      const int f = frag - F5F;
      plane = f & 1;
      const int c = (f >> 1) & 3, kcch = f >> 3, kc = kcch % 5, ch = kcch / 5;
      n = ch * 64 + c * 16 + nn; k = kc * 32 + quad * 8 + j;
      w = ((k < 128) ? a[(3 + k) * 128 + n]
        : (k < 131) ? a[(k - 128) * 128 + n] : 0.f) * LOG2E;
    }
    unsigned short hu, lu; split2(w, hu, lu);
    g_Wf[i] = plane ? lu : hu;
  }
}

// ---- shared LDS strides ----
#define XAs 88    // u16 stride (fps kernel only)
#define XHs 152   // u16 stride; bank step 12 mod 32 -> balanced b128 reads

// fps MLP+ebias via MFMA: 16 points/block, 1024 blocks. Split-bf16
// activations, 3-term products ~= fp32 precision.
__global__ __launch_bounds__(256) void fps_kernel(
    const int* __restrict__ fps_idx, float* __restrict__ out)
{
  __shared__ __align__(16) unsigned char LB[15376];
  unsigned short* XAh = (unsigned short*)(LB + 0);
  unsigned short* XAl = (unsigned short*)(LB + 2816);
  unsigned short* XHh = (unsigned short*)(LB + 5632);
  unsigned short* XHl = (unsigned short*)(LB + 10496);
  unsigned short* ZS  = (unsigned short*)(LB + 15360);

  const int t = threadIdx.x, lane = t & 63, w = t >> 6;
  const int quad = lane >> 4, nn = lane & 15;
  const int ch = w >> 1, cl = w & 1;
  const int blk = ((blockIdx.x & 7) << 7) | (blockIdx.x >> 3);  // XCD swizzle
  const int g0 = blk * 16;

  if (t < 4) ((float*)ZS)[t] = 0.f;

  // gather 16 fps rows, split hi/lo
  if (t < 128) {
    const int s0 = t >> 3, cg = t & 7;
    const int gp = g0 + s0, b = gp >> 10, p = gp & 1023;
    const int fi = fps_idx[gp];
    const float* frow = g_pts + (((long)b << 12) + fi) * 68;
    const int c0 = cg * 8;
    const float4 va = *(const float4*)(frow + c0);
    const float4 vb = *(const float4*)(frow + c0 + 4);
    short8 hv, lv;
    unsigned short hu, lu;
    split2(va.x, hu, lu); hv[0] = (short)hu; lv[0] = (short)lu;
    split2(va.y, hu, lu); hv[1] = (short)hu; lv[1] = (short)lu;
    split2(va.z, hu, lu); hv[2] = (short)hu; lv[2] = (short)lu;
    split2(va.w, hu, lu); hv[3] = (short)hu; lv[3] = (short)lu;
    split2(vb.x, hu, lu); hv[4] = (short)hu; lv[4] = (short)lu;
    split2(vb.y, hu, lu); hv[5] = (short)hu; lv[5] = (short)lu;
    split2(vb.z, hu, lu); hv[6] = (short)hu; lv[6] = (short)lu;
    split2(vb.w, hu, lu); hv[7] = (short)hu; lv[7] = (short)lu;
    *(short8*)(XAh + s0 * XAs + c0) = hv;
    *(short8*)(XAl + s0 * XAs + c0) = lv;
    if (cg == 0) {
      #pragma unroll
      for (int d = 0; d < 3; ++d) {
        const float v = frow[64 + d];
        unsigned short h2, l2; split2(v, h2, l2);
        XAh[s0 * XAs + 64 + d] = h2; XAl[s0 * XAs + 64 + d] = l2;
        XHh[s0 * XHs + 128 + d] = h2; XHl[s0 * XHs + 128 + d] = l2;
        out[(b * 3 + d) * Pn + p] = v;
        g_fps[(long)gp * 132 + 128 + d] = v;
      }
    } else if (cg == 1) {
      #pragma unroll
      for (int j = 0; j < 13; ++j) { XAh[s0 * XAs + 67 + j] = 0; XAl[s0 * XAs + 67 + j] = 0; }
    } else if (cg == 2) {
      #pragma unroll
      for (int j = 0; j < 13; ++j) { XHh[s0 * XHs + 131 + j] = 0; XHl[s0 * XHs + 131 + j] = 0; }
    }
  }
  __syncthreads();

  f32x4 C[2];
  const int col1 = w * 16 + nn;

  // Phase 1: X(K96) @ W1 -> h1 (bias in acc init)
  {
    const float bb = g_W[B1O + col1];
    C[0] = (f32x4){bb, bb, bb, bb};
  }
  #pragma unroll
  for (int kc = 0; kc < 3; ++kc) {
    const int ka = kc * 32 + quad * 8;
    const short8 A0h = (ka < 80) ? *(const short8*)(XAh + nn * XAs + ka) : *(const short8*)ZS;
    const short8 A0l = (ka < 80) ? *(const short8*)(XAl + nn * XAs + ka) : *(const short8*)ZS;
    const unsigned short* pf = g_Wf + (((ch * 3 + kc) * 2 + cl) * 2) * 512 + lane * 8;
    const short8 Bh = *(const short8*)pf, Bl = *(const short8*)(pf + 512);
    TERM3(C[0], A0h, A0l, Bh, Bl);
  }
  #pragma unroll
  for (int r = 0; r < 4; ++r) {
    const float v = fmaxf(C[0][r], 0.f);
    unsigned short hu, lu; split2(v, hu, lu);
    XHh[(quad * 4 + r) * XHs + col1] = hu;
    XHl[(quad * 4 + r) * XHs + col1] = lu;
  }
  __syncthreads();

  // Phase 2: h1(K64) @ W2 -> h2
  {
    const float bb = g_W[B2O + col1];
    C[0] = (f32x4){bb, bb, bb, bb};
  }
  #pragma unroll
  for (int kc = 0; kc < 2; ++kc) {
    const int ka = kc * 32 + quad * 8;
    const short8 A0h = *(const short8*)(XHh + nn * XHs + ka);
    const short8 A0l = *(const short8*)(XHl + nn * XHs + ka);
    const unsigned short* pf = g_Wf + (F2F + ((ch * 2 + kc) * 2 + cl) * 2) * 512 + lane * 8;
    const short8 Bh = *(const short8*)pf, Bl = *(const short8*)(pf + 512);
    TERM3(C[0], A0h, A0l, Bh, Bl);
  }
  __syncthreads();
  #pragma unroll
  for (int r = 0; r < 4; ++r) {
    const float v = fmaxf(C[0][r], 0.f);
    unsigned short hu, lu; split2(v, hu, lu);
    XAh[(quad * 4 + r) * XAs + col1] = hu;
    XAl[(quad * 4 + r) * XAs + col1] = lu;
  }
  __syncthreads();

  // Phase 3: h2(K64) @ W3 -> h3 (128 cols)
  {
    const float b0 = g_W[B3O + w * 32 + nn];
    const float b1 = g_W[B3O + w * 32 + 16 + nn];
    C[0] = (f32x4){b0, b0, b0, b0};
    C[1] = (f32x4){b1, b1, b1, b1};
  }
  #pragma unroll
  for (int kc = 0; kc < 2; ++kc) {
    const int ka = kc * 32 + quad * 8;
    const short8 A0h = *(const short8*)(XAh + nn * XAs + ka);
    const short8 A0l = *(const short8*)(XAl + nn * XAs + ka);
    #pragma unroll
    for (int c2 = 0; c2 < 2; ++c2) {
      const unsigned short* pf = g_Wf + (F3F + ((ch * 2 + kc) * 4 + cl * 2 + c2) * 2) * 512 + lane * 8;
      const short8 Bh = *(const short8*)pf, Bl = *(const short8*)(pf + 512);
      TERM3(C[c2], A0h, A0l, Bh, Bl);
    }
  }
  __syncthreads();
  #pragma unroll
  for (int c2 = 0; c2 < 2; ++c2) {
    const int col = w * 32 + c2 * 16 + nn;
    #pragma unroll
    for (int r = 0; r < 4; ++r) {
      const float v = fmaxf(C[c2][r], 0.f);
      unsigned short hu, lu; split2(v, hu, lu);
      XHh[(quad * 4 + r) * XHs + col] = hu;
      XHl[(quad * 4 + r) * XHs + col] = lu;
    }
  }
  __syncthreads();

  // Phase 5: [h3|xyz](K160) @ A(log2e-scaled) -> ebias' -> g_fps
  C[0] = (f32x4){0.f,0.f,0.f,0.f}; C[1] = C[0];
  #pragma unroll
  for (int kc = 0; kc < 5; ++kc) {
    const int ka = kc * 32 + quad * 8;
    const short8 A0h = (ka < 144) ? *(const short8*)(XHh + nn * XHs + ka) : *(const short8*)ZS;
    const short8 A0l = (ka < 144) ? *(const short8*)(XHl + nn * XHs + ka) : *(const short8*)ZS;
    #pragma unroll
    for (int c2 = 0; c2 < 2; ++c2) {
      const unsigned short* pf = g_Wf + (F5F + ((ch * 5 + kc) * 4 + cl * 2 + c2) * 2) * 512 + lane * 8;
      const short8 Bh = *(const short8*)pf, Bl = *(const short8*)(pf + 512);
      TERM3(C[c2], A0h, A0l, Bh, Bl);
    }
  }
  #pragma unroll
  for (int c2 = 0; c2 < 2; ++c2) {
    const int col = w * 32 + c2 * 16 + nn;
    #pragma unroll
    for (int r = 0; r < 4; ++r)
      g_fps[(long)(g0 + quad * 4 + r) * 132 + col] = C[c2][r];
  }
}

// Epilogue: g_tmp[b][p][128] -> out1[b][c][p]
__global__ __launch_bounds__(256) void transpose_out(float* __restrict__ out)
{
  __shared__ float T[64 * 129];
  const int t = threadIdx.x;
  const int b = blockIdx.x >> 4, p0 = (blockIdx.x & 15) << 6;
  const int c = t & 127, ph = t >> 7;
  #pragma unroll
  for (int pp = 0; pp < 32; ++pp) {
    const int pi = ph * 32 + pp;
    T[pi * 129 + c] = g_tmp[(((long)b << 10) + p0 + pi) * 128 + c];
  }
  __syncthreads();
  const int pn = t & 63, cg = t >> 6;
  #pragma unroll
  for (int k = 0; k < 32; ++k) {
    const int cc = cg * 32 + k;
    out[Bn * 3 * Pn + ((b << 7) + cc) * Pn + p0 + pn] = T[pn * 129 + cc];
  }
}

// ---- fused kernel: R8 structure EXACTLY (2 groups/block, overlaid [32][152]
// buffers, ebias' in XB padding holes, dense g_tmp write) with the one
// untested launch-bounds point: (256,6) -> VGPR cap 85.
// Register-band facts: cap 102 clean (R5), cap 73 spills ~16B/thr (R8),
// cap 64 spills catastrophically (R7/R9). Need is in (73,102].
// A/B read: WRITE_SIZE ~8.5MB => clean, keep; WRITE >30MB => next is (256,5).
#define OXB0 0            // 32*152*2 = 9728
#define OXB1 9728         // -> 19456
#define OZS  19456        // 16 B zero stub -> 19472
#define LDSB 19472

// FS float at hole: row (cc>>2), u16 col 144 + (cc&3)*2  (4B-aligned)
#define FS_PTR(XBg, cc) ((float*)((XBg) + ((cc) >> 2) * XHs + 144 + ((cc) & 3) * 2))

__global__ __launch_bounds__(256, 6) void fused_kernel(
    const int* __restrict__ group_idx)
{
  __shared__ __align__(16) unsigned char LB[LDSB];
  unsigned short* const XB0 = (unsigned short*)(LB + OXB0);
  unsigned short* const XB1 = (unsigned short*)(LB + OXB1);
  unsigned short* ZS = (unsigned short*)(LB + OZS);

  const int t = threadIdx.x, lane = t & 63, w = t >> 6;
  const int quad = lane >> 4, nn = lane & 15;
  const int ch = w >> 1, cl = w & 1;
  // XCD swizzle: 8192 blocks -> each XCD gets 1024 contiguous blocks
  const int blk = ((blockIdx.x & 7) << 10) | (blockIdx.x >> 3);
  const int base = blk * 2;            // groups base, base+1 (same b always)
  const int b = base >> 10;

  // ---- S0: stage ebias' into XB padding holes; zero stub ----
  {
    const int gi = t >> 7, cc = t & 127;
    unsigned short* XBg = gi ? XB1 : XB0;
    *FS_PTR(XBg, cc) = g_fps[(long)(base + gi) * 132 + cc];
  }
  if (t < 4) ((float*)ZS)[t] = 0.f;

  // ---- S1: gather group rows; rxyz at 64..66 AND 128..130; zero pads ----
  {
    const int s0 = t >> 3, cg = t & 7;
    const int c0 = cg * 8;
    #pragma unroll
    for (int gi = 0; gi < 2; ++gi) {
      unsigned short* XBg = gi ? XB1 : XB0;
      const int gidx = group_idx[(base + gi) * Sn + s0];
      const float* prow = g_pts + (((long)b << 12) + gidx) * 68;
      const float4 va = *(const float4*)(prow + c0);
      const float4 vb = *(const float4*)(prow + c0 + 4);
      unsigned q0, q1, q2, q3;
      asm("v_cvt_pk_bf16_f32 %0, %1, %2" : "=v"(q0) : "v"(va.x), "v"(va.y));
      asm("v_cvt_pk_bf16_f32 %0, %1, %2" : "=v"(q1) : "v"(va.z), "v"(va.w));
      asm("v_cvt_pk_bf16_f32 %0, %1, %2" : "=v"(q2) : "v"(vb.x), "v"(vb.y));
      asm("v_cvt_pk_bf16_f32 %0, %1, %2" : "=v"(q3) : "v"(vb.z), "v"(vb.w));
      uint4 hv = {q0, q1, q2, q3};
      *(uint4*)(XBg + s0 * XHs + c0) = hv;
      if (cg == 0) {
        #pragma unroll
        for (int d = 0; d < 3; ++d) {
          const float r = prow[64 + d] - g_fps[(long)(base + gi) * 132 + 128 + d];
          const unsigned short hu = bfh(r);
          XBg[s0 * XHs + 64 + d] = hu;
          XBg[s0 * XHs + 128 + d] = hu;
        }
      } else if (cg == 1) {
        #pragma unroll
        for (int j = 0; j < 15; ++j) XBg[s0 * XHs + 67 + j] = 0;   // 67..81
      } else if (cg == 2) {
        #pragma unroll
        for (int j = 0; j < 14; ++j) XBg[s0 * XHs + 82 + j] = 0;   // 82..95
      } else if (cg == 3) {
        #pragma unroll
        for (int j = 0; j < 13; ++j) XBg[s0 * XHs + 131 + j] = 0;  // 131..143
      }
    }
  }
  __syncthreads();

  const int col1 = w * 16 + nn;

  // ===== Phase 1: X(cols 0..95) @ W1f -> h1 (cols 0..63) =====
  {
    f32x4 C00, C01, C10, C11;
    const float bb = g_W[B1O + col1];
    C00 = (f32x4){bb, bb, bb, bb};
    C01 = C00; C10 = C00; C11 = C00;
    #pragma unroll
    for (int kc = 0; kc < 3; ++kc) {
      const int ka = kc * 32 + quad * 8;
      const unsigned short* pf = g_Wf + (((ch * 3 + kc) * 2 + cl) * 2) * 512 + lane * 8;
      const short8 Bh = *(const short8*)pf, Bl = *(const short8*)(pf + 512);
      const short8 A00 = *(const short8*)(XB0 + nn * XHs + ka);
      const short8 A01 = *(const short8*)(XB0 + (16 + nn) * XHs + ka);
      const short8 A10 = *(const short8*)(XB1 + nn * XHs + ka);
      const short8 A11 = *(const short8*)(XB1 + (16 + nn) * XHs + ka);
      C00 = MFMA_BF16(A00, Bh, C00, 0, 0, 0);
      C00 = MFMA_BF16(A00, Bl, C00, 0, 0, 0);
      C01 = MFMA_BF16(A01, Bh, C01, 0, 0, 0);
      C01 = MFMA_BF16(A01, Bl, C01, 0, 0, 0);
      C10 = MFMA_BF16(A10, Bh, C10, 0, 0, 0);
      C10 = MFMA_BF16(A10, Bl, C10, 0, 0, 0);
      C11 = MFMA_BF16(A11, Bh, C11, 0, 0, 0);
      C11 = MFMA_BF16(A11, Bl, C11, 0, 0, 0);
    }
    __syncthreads();   // all X reads complete before h1 overwrites cols 0..63
    #pragma unroll
    for (int r = 0; r < 4; ++r) {
      XB0[(quad * 4 + r) * XHs + col1]      = bfh(fmaxf(C00[r], 0.f));
      XB0[(16 + quad * 4 + r) * XHs + col1] = bfh(fmaxf(C01[r], 0.f));
      XB1[(quad * 4 + r) * XHs + col1]      = bfh(fmaxf(C10[r], 0.f));
      XB1[(16 + quad * 4 + r) * XHs + col1] = bfh(fmaxf(C11[r], 0.f));
    }
  }
  __syncthreads();

  // ===== Phase 2: h1(cols 0..63) @ W2f -> h2 (cols 64..127, disjoint) =====
  {
    f32x4 C00, C01, C10, C11;
    const float bb = g_W[B2O + col1];
    C00 = (f32x4){bb, bb, bb, bb};
    C01 = C00; C10 = C00; C11 = C00;
    #pragma unroll
    for (int kc = 0; kc < 2; ++kc) {
      const int ka = kc * 32 + quad * 8;
      const unsigned short* pf = g_Wf + (F2F + ((ch * 2 + kc) * 2 + cl) * 2) * 512 + lane * 8;
      const short8 Bh = *(const short8*)pf, Bl = *(const short8*)(pf + 512);
      const short8 A00 = *(const short8*)(XB0 + nn * XHs + ka);
      const short8 A01 = *(const short8*)(XB0 + (16 + nn) * XHs + ka);
      const short8 A10 = *(const short8*)(XB1 + nn * XHs + ka);
      const short8 A11 = *(const short8*)(XB1 + (16 + nn) * XHs + ka);
      C00 = MFMA_BF16(A00, Bh, C00, 0, 0, 0);
      C00 = MFMA_BF16(A00, Bl, C00, 0, 0, 0);
      C01 = MFMA_BF16(A01, Bh, C01, 0, 0, 0);
      C01 = MFMA_BF16(A01, Bl, C01, 0, 0, 0);
      C10 = MFMA_BF16(A10, Bh, C10, 0, 0, 0);
      C10 = MFMA_BF16(A10, Bl, C10, 0, 0, 0);
      C11 = MFMA_BF16(A11, Bh, C11, 0, 0, 0);
      C11 = MFMA_BF16(A11, Bl, C11, 0, 0, 0);
    }
    #pragma unroll
    for (int r = 0; r < 4; ++r) {
      XB0[(quad * 4 + r) * XHs + 64 + col1]      = bfh(fmaxf(C00[r], 0.f));
      XB0[(16 + quad * 4 + r) * XHs + 64 + col1] = bfh(fmaxf(C01[r], 0.f));
      XB1[(quad * 4 + r) * XHs + 64 + col1]      = bfh(fmaxf(C10[r], 0.f));
      XB1[(16 + quad * 4 + r) * XHs + 64 + col1] = bfh(fmaxf(C11[r], 0.f));
    }
  }
  __syncthreads();

  // ===== Phase 3: h2(cols 64..127) @ W3f -> h3 (cols 0..127) =====
  {
    f32x4 C0[4], C1[4];   // [mi*2+c2] for group0, group1
    const float b0 = g_W[B3O + w * 32 + nn];
    const float b1 = g_W[B3O + w * 32 + 16 + nn];
    C0[0] = (f32x4){b0, b0, b0, b0};
    C0[1] = (f32x4){b1, b1, b1, b1};
    C0[2] = C0[0]; C0[3] = C0[1];
    C1[0] = C0[0]; C1[1] = C0[1]; C1[2] = C0[0]; C1[3] = C0[1];
    #pragma unroll
    for (int kc = 0; kc < 2; ++kc) {
      const int ka = 64 + kc * 32 + quad * 8;
      const short8 A00 = *(const short8*)(XB0 + nn * XHs + ka);
      const short8 A01 = *(const short8*)(XB0 + (16 + nn) * XHs + ka);
      const short8 A10 = *(const short8*)(XB1 + nn * XHs + ka);
      const short8 A11 = *(const short8*)(XB1 + (16 + nn) * XHs + ka);
      #pragma unroll
      for (int c2 = 0; c2 < 2; ++c2) {
        const unsigned short* pf = g_Wf + (F3F + ((ch * 2 + kc) * 4 + cl * 2 + c2) * 2) * 512 + lane * 8;
        const short8 Bh = *(const short8*)pf, Bl = *(const short8*)(pf + 512);
        C0[0 + c2] = MFMA_BF16(A00, Bh, C0[0 + c2], 0, 0, 0);
        C0[0 + c2] = MFMA_BF16(A00, Bl, C0[0 + c2], 0, 0, 0);
        C0[2 + c2] = MFMA_BF16(A01, Bh, C0[2 + c2], 0, 0, 0);
        C0[2 + c2] = MFMA_BF16(A01, Bl, C0[2 + c2], 0, 0, 0);
        C1[0 + c2] = MFMA_BF16(A10, Bh, C1[0 + c2], 0, 0, 0);
        C1[0 + c2] = MFMA_BF16(A10, Bl, C1[0 + c2], 0, 0, 0);
        C1[2 + c2] = MFMA_BF16(A11, Bh, C1[2 + c2], 0, 0, 0);
        C1[2 + c2] = MFMA_BF16(A11, Bl, C1[2 + c2], 0, 0, 0);
      }
    }
    __syncthreads();   // all h2 reads complete before h3 overwrites 0..127
    #pragma unroll
    for (int c2 = 0; c2 < 2; ++c2) {
      const int col = w * 32 + c2 * 16 + nn;
      #pragma unroll
      for (int r = 0; r < 4; ++r) {
        XB0[(quad * 4 + r) * XHs + col]      = bfh(fmaxf(C0[0 + c2][r], 0.f));
        XB0[(16 + quad * 4 + r) * XHs + col] = bfh(fmaxf(C0[2 + c2][r], 0.f));
        XB1[(quad * 4 + r) * XHs + col]      = bfh(fmaxf(C1[0 + c2][r], 0.f));
        XB1[(16 + quad * 4 + r) * XHs + col] = bfh(fmaxf(C1[2 + c2][r], 0.f));
      }
    }
  }
  __syncthreads();

  // ===== Phase 5: [h3|rxyz](cols 0..143) @ Af(log2e) -> scores (regs) =====
  // acc init = -ebias' (read from LDS holes)  =>  t = min(C, 0.2C)
  f32x4 C0[4], C1[4];
  {
    const float e00 = *FS_PTR(XB0, w * 32 + nn);
    const float e01 = *FS_PTR(XB0, w * 32 + 16 + nn);
    const float e10 = *FS_PTR(XB1, w * 32 + nn);
    const float e11 = *FS_PTR(XB1, w * 32 + 16 + nn);
    C0[0] = (f32x4){-e00, -e00, -e00, -e00};
    C0[1] = (f32x4){-e01, -e01, -e01, -e01};
    C0[2] = C0[0]; C0[3] = C0[1];
    C1[0] = (f32x4){-e10, -e10, -e10, -e10};
    C1[1] = (f32x4){-e11, -e11, -e11, -e11};
    C1[2] = C1[0]; C1[3] = C1[1];
  }
  #pragma unroll
  for (int kc = 0; kc < 5; ++kc) {
    const int ka = kc * 32 + quad * 8;
    const short8 A00 = (ka < 144) ? *(const short8*)(XB0 + nn * XHs + ka) : *(const short8*)ZS;
    const short8 A01 = (ka < 144) ? *(const short8*)(XB0 + (16 + nn) * XHs + ka) : *(const short8*)ZS;
    const short8 A10 = (ka < 144) ? *(const short8*)(XB1 + nn * XHs + ka) : *(const short8*)ZS;
    const short8 A11 = (ka < 144) ? *(const short8*)(XB1 + (16 + nn) * XHs + ka) : *(const short8*)ZS;
    #pragma unroll
    for (int c2 = 0; c2 < 2; ++c2) {
      const unsigned short* pf = g_Wf + (F5F + ((ch * 5 + kc) * 4 + cl * 2 + c2) * 2) * 512 + lane * 8;
      const short8 Bh = *(const short8*)pf, Bl = *(const short8*)(pf + 512);
      C0[0 + c2] = MFMA_BF16(A00, Bh, C0[0 + c2], 0, 0, 0);
      C0[0 + c2] = MFMA_BF16(A00, Bl, C0[0 + c2], 0, 0, 0);
      C0[2 + c2] = MFMA_BF16(A01, Bh, C0[2 + c2], 0, 0, 0);
      C0[2 + c2] = MFMA_BF16(A01, Bl, C0[2 + c2], 0, 0, 0);
      C1[0 + c2] = MFMA_BF16(A10, Bh, C1[0 + c2], 0, 0, 0);
      C1[0 + c2] = MFMA_BF16(A10, Bl, C1[0 + c2], 0, 0, 0);
      C1[2 + c2] = MFMA_BF16(A11, Bh, C1[2 + c2], 0, 0, 0);
      C1[2 + c2] = MFMA_BF16(A11, Bl, C1[2 + c2], 0, 0, 0);
    }
  }

  // ---- wave-local softmax + pool; dense block-local g_tmp write ----
  #pragma unroll
  for (int gi = 0; gi < 2; ++gi) {
    unsigned short* XBg = gi ? XB1 : XB0;
    #pragma unroll
    for (int c2 = 0; c2 < 2; ++c2) {
      const int col = w * 32 + c2 * 16 + nn;
      f32x4* Cg = gi ? C1 : C0;
      float tmin = 3.4e38f;
      #pragma unroll
      for (int mi = 0; mi < 2; ++mi)
        #pragma unroll
        for (int r = 0; r < 4; ++r) {
          const int idx = mi * 2 + c2;
          const float cv = Cg[idx][r];
          const float tv = fminf(cv, 0.2f * cv);
          Cg[idx][r] = tv;
          tmin = fminf(tmin, tv);
        }
      tmin = fminf(tmin, __shfl_xor(tmin, 16));
      tmin = fminf(tmin, __shfl_xor(tmin, 32));
      float den = 0.f, pool = 0.f;
      #pragma unroll
      for (int mi = 0; mi < 2; ++mi)
        #pragma unroll
        for (int r = 0; r < 4; ++r) {
          const int idx = mi * 2 + c2;
          const float wgt = __builtin_amdgcn_exp2f(tmin - Cg[idx][r]);
          den += wgt;
          pool = fmaf(wgt, bf2f(XBg[(mi * 16 + quad * 4 + r) * XHs + col]), pool);
        }
      den  += __shfl_xor(den, 16);  den  += __shfl_xor(den, 32);
      pool += __shfl_xor(pool, 16); pool += __shfl_xor(pool, 32);
      if (quad == 0)
        g_tmp[(long)(base + gi) * 128 + col] =
            pool * __builtin_amdgcn_rcpf(den);
    }
  }
}

extern "C" void kernel_launch(void* const* d_in, const int* in_sizes, int n_in,
                              void* d_out, int out_size, void* d_ws, size_t ws_size,
                              hipStream_t stream) {
  const float* xyz       = (const float*)d_in[0];
  const float* points    = (const float*)d_in[1];
  const int*   fps_idx   = (const int*)d_in[2];
  const int*   group_idx = (const int*)d_in[3];

  const int prep_blocks = 1024 + (WSF + WFU + 255) / 256;
  prep_kernel<<<prep_blocks, 256, 0, stream>>>(
      xyz, points,
      (const float*)d_in[4],  (const float*)d_in[5],
      (const float*)d_in[6],  (const float*)d_in[7],
      (const float*)d_in[8],  (const float*)d_in[9],
      (const float*)d_in[10], (const float*)d_in[11],
      (const float*)d_in[12], (const float*)d_in[13],
      (const float*)d_in[14], (const float*)d_in[15],
      (const float*)d_in[16], (const float*)d_in[17],
      (const float*)d_in[18], (const float*)d_in[19],
      (const float*)d_in[20], (const float*)d_in[21],
      (const float*)d_in[22]);

  fps_kernel<<<1024, 256, 0, stream>>>(fps_idx, (float*)d_out);

  fused_kernel<<<Bn * Pn / 2, 256, 0, stream>>>(group_idx);

  transpose_out<<<Bn * 16, 256, 0, stream>>>((float*)d_out);
}